// Round 10
// baseline (101.661 us; speedup 1.0000x reference)
//
#include <hip/hip_runtime.h>

#define HH 128
#define WW 128
// 1 wave per (n,c) plane, 2 rows/lane (lane l owns rows 2l, 2l+1), __shfl
// neighbor exchange (r1-proven) — no LDS, no barriers.
// HARD RULE (r4/r7/r8/r9 post-mortem): inline-asm "v" operands live in arch
// VGPRs v0-v255 ONLY (AGPRs are not reachable by "v" constraints), so pinned
// f4 liveness must stay <= ~220. This kernel's peak = 50 f4 = 200 regs:
// SW=16 cols/window, ping-pong buffers, staggered prefetch (tranche1 {b,x}
// early, tranche2 {a,c,d} mid-scan).
// SW=16 half-line granularity is safe for HBM fetch because consecutive
// windows are ~0.6us apart in wall time -> L2 retains the 128B line between
// the two half-touches (r5's 1.9x amp came from 5us barrier-stretched gaps).

typedef float f4 __attribute__((ext_vector_type(4)));

// ---- inline-asm VMEM: order pinned, counted vmcnt valid ----
#define GLOAD(dst, ptr, OFF)                                                  \
    asm volatile("global_load_dwordx4 %0, %1, off offset:%2"                  \
                 : "=&v"(dst) : "v"(ptr), "n"(OFF) : "memory");

#define GSTORE(val, ptr, OFF)                                                 \
    asm volatile("global_store_dwordx4 %0, %1, off offset:%2"                 \
                 :: "v"(ptr), "v"(val), "n"(OFF) : "memory");

#define VMCNT_(N)                                                             \
    asm volatile("s_waitcnt vmcnt(" #N ")" ::: "memory");                     \
    __builtin_amdgcn_sched_barrier(0);
#define VMCNT(N) VMCNT_(N)

// one operand, one window: 4 f4 row 2l (WOFF..WOFF+48) + 4 f4 row 2l+1
// (+512 bytes = one row)
#define LD8(n0, n1, ptr, WOFF)                                                \
    GLOAD(n0##0, ptr, (WOFF)+0)    GLOAD(n0##1, ptr, (WOFF)+16)               \
    GLOAD(n0##2, ptr, (WOFF)+32)   GLOAD(n0##3, ptr, (WOFF)+48)               \
    GLOAD(n1##0, ptr, (WOFF)+512)  GLOAD(n1##1, ptr, (WOFF)+528)              \
    GLOAD(n1##2, ptr, (WOFF)+544)  GLOAD(n1##3, ptr, (WOFF)+560)

#define LDT1(P, WOFF)  LD8(P##b, P##B, bp, WOFF) LD8(P##x, P##X, xp, WOFF)
#define LDT2(P, WOFF)  LD8(P##a, P##A, ap, WOFF) LD8(P##c, P##C, cp, WOFF)    \
                       LD8(P##d, P##D, dp, WOFF)

#define STH1(P, WOFF)                                                         \
    GSTORE(P##x0, op, (WOFF)+0)    GSTORE(P##x1, op, (WOFF)+16)               \
    GSTORE(P##X0, op, (WOFF)+512)  GSTORE(P##X1, op, (WOFF)+528)

#define STH2(P, WOFF)                                                         \
    GSTORE(P##x2, op, (WOFF)+32)   GSTORE(P##x3, op, (WOFF)+48)               \
    GSTORE(P##X2, op, (WOFF)+544)  GSTORE(P##X3, op, (WOFF)+560)

#define DECLROW4(s) f4 s##0, s##1, s##2, s##3;
#define DECLBUF(P)                                                            \
    DECLROW4(P##x) DECLROW4(P##X) DECLROW4(P##b) DECLROW4(P##B)               \
    DECLROW4(P##a) DECLROW4(P##A) DECLROW4(P##c) DECLROW4(P##C)               \
    DECLROW4(P##d) DECLROW4(P##D)

#define MUL4(u, v)                                                            \
    { (u)[0]*=(v)[0]; (u)[1]*=(v)[1]; (u)[2]*=(v)[2]; (u)[3]*=(v)[3]; }

#define FUSE(P)                                                               \
    MUL4(P##x0,P##b0) MUL4(P##x1,P##b1) MUL4(P##x2,P##b2) MUL4(P##x3,P##b3)   \
    MUL4(P##X0,P##B0) MUL4(P##X1,P##B1) MUL4(P##X2,P##B2) MUL4(P##X3,P##B3)

// One scan step (r1-proven formula + exchange):
// row 2l:   h0 = bx + G1*(lane l-1's hp1) + G2*hp0 + G3*hp1
// row 2l+1: h1 = bx + G1*hp0 + G2*hp1 + G3*(lane l+1's hp0)
#define STEP1(P, v, k) do {                                                   \
        float up = __shfl_up(hp1, 1);                                         \
        float dn = __shfl_down(hp0, 1);                                       \
        if (t == 0)  up = 0.f;                                                \
        if (t == 63) dn = 0.f;                                                \
        const float h0 = P##x##v[k] + P##a##v[k]*up  + P##c##v[k]*hp0         \
                                    + P##d##v[k]*hp1;                         \
        const float h1 = P##X##v[k] + P##A##v[k]*hp0 + P##C##v[k]*hp1         \
                                    + P##D##v[k]*dn;                          \
        hp0 = h0; hp1 = h1;                                                   \
        P##x##v[k] = h0; P##X##v[k] = h1;                                     \
    } while (0)

#define STEP4(P, v) STEP1(P,v,0); STEP1(P,v,1); STEP1(P,v,2); STEP1(P,v,3);

// Scan window P (16 steps), prefetch Q staggered: LDT1 {b,x} before the
// scan; LDT2 {a,c,d} after group 2 (P's freed regs cover the budget).
// Peak live = 10 f4 (P remnants) + 40 f4 (Q) = 50 f4 = 200 VGPRs.
#define WINDOW_PF(P, Q, WOFF, NOFF)                                           \
    FUSE(P)                                                                   \
    LDT1(Q, NOFF)                                                             \
    STEP4(P,0) STEP4(P,1)                                                     \
    STH1(P, WOFF)                                                             \
    STEP4(P,2)                                                                \
    LDT2(Q, NOFF)                                                             \
    STEP4(P,3)                                                                \
    STH2(P, WOFF)

#define WINDOW_LAST(P, WOFF)                                                  \
    FUSE(P)                                                                   \
    STEP4(P,0) STEP4(P,1)                                                     \
    STH1(P, WOFF)                                                             \
    STEP4(P,2) STEP4(P,3)                                                     \
    STH2(P, WOFF)

// Boundary VMCNT(4): 4 newest outstanding = previous window's STH2; vmcnt
// retires in issue order, so <=4 outstanding implies both prefetch tranches
// (older) have landed.
__global__ __launch_bounds__(64, 1) void gr2d_kernel(
    const float* __restrict__ X, const float* __restrict__ Bm,
    const float* __restrict__ G1, const float* __restrict__ G2,
    const float* __restrict__ G3, float* __restrict__ Out)
{
    const int t = threadIdx.x;                               // lane 0..63
    const size_t rb = (size_t)blockIdx.x * (HH * WW) + (size_t)(2 * t) * WW;
    const float* xp = X  + rb;
    const float* bp = Bm + rb;
    const float* ap = G1 + rb;
    const float* cp = G2 + rb;
    const float* dp = G3 + rb;
    float*       op = Out + rb;

    float hp0 = 0.f, hp1 = 0.f;      // H[2l, w-1], H[2l+1, w-1]

    DECLBUF(A)
    DECLBUF(B)

    // prologue: window 0 fully in flight (40 loads)
    LDT1(A, 0) LDT2(A, 0)

    VMCNT(0)  WINDOW_PF(A, B, 0,   64)
    VMCNT(4)  WINDOW_PF(B, A, 64,  128)
    VMCNT(4)  WINDOW_PF(A, B, 128, 192)
    VMCNT(4)  WINDOW_PF(B, A, 192, 256)
    VMCNT(4)  WINDOW_PF(A, B, 256, 320)
    VMCNT(4)  WINDOW_PF(B, A, 320, 384)
    VMCNT(4)  WINDOW_PF(A, B, 384, 448)
    VMCNT(4)  WINDOW_LAST(B, 448)

    // drain asm stores before endpgm (compiler doesn't track them)
    asm volatile("s_waitcnt vmcnt(0)" ::: "memory");
}

extern "C" void kernel_launch(void* const* d_in, const int* in_sizes, int n_in,
                              void* d_out, int out_size, void* d_ws, size_t ws_size,
                              hipStream_t stream) {
    const float* X  = (const float*)d_in[0];
    const float* Bm = (const float*)d_in[1];
    const float* G1 = (const float*)d_in[2];
    const float* G2 = (const float*)d_in[3];
    const float* G3 = (const float*)d_in[4];
    float* Out = (float*)d_out;

    const int planes = in_sizes[0] / (HH * WW);   // 8*96 = 768
    gr2d_kernel<<<dim3(planes), dim3(64), 0, stream>>>(X, Bm, G1, G2, G3, Out);
}